// Round 2
// baseline (498.336 us; speedup 1.0000x reference)
//
#include <hip/hip_runtime.h>
#include <hip/hip_bf16.h>

// GraphConvolution: x[B,N,D] fp32, W[K,D,O] fp32, COO edges per support (fp32 vals).
// out[b][n][k*O+o] = sum_{edges (r=n,c) in support k} val * (x[b][c][:] @ W[k][:,o])
constexpr int B = 16, N = 10000, D = 128, O = 64, K = 3, E = 160000;
constexpr int BO = B * O;   // 1024
constexpr int KO = K * O;   // 192
constexpr int XS_STRIDE = 20;  // LDS pad: float4-aligned (20%4==0), breaks pow2 bank stride

__device__ __forceinline__ float bf2f(unsigned short u) {
  return __uint_as_float(((unsigned int)u) << 16);
}
// fp32 -> bf16 round-to-nearest-even (finite inputs)
__device__ __forceinline__ unsigned short f2bf(float f) {
  unsigned int u = __float_as_uint(f);
  u += 0x7FFFu + ((u >> 16) & 1u);
  return (unsigned short)(u >> 16);
}

// ---------------------------------------------------------------------------
// Kernel 1: pre[kloc][n][b*64+o] = sum_d x[b][n][d] * W[kBase+kloc][d][o]
// fp32 inputs, fp32 accumulate, bf16 store (pre is scratch; halves gather BW).
// One block per n; blockDim = 64*kCount, wave w handles support kBase+w.
// Thread: 4x4 (b,o) register tile -> 16 FMA per d per thread.
// ---------------------------------------------------------------------------
__global__ __launch_bounds__(192) void gemm_pre_kernel(
    const float* __restrict__ x,          // [B][N][D] fp32
    const float* __restrict__ w,          // [K][D][O] fp32
    unsigned short* __restrict__ pre,     // [kCount][N][BO] bf16 (local k indexing)
    int kBase)
{
  __shared__ float xs[D * XS_STRIDE];     // xs[d*XS_STRIDE + b]
  const int n = blockIdx.x;
  const int t = threadIdx.x;

  // Stage x[b][n][0..127] for all 16 b, transposed to [d][b].
  for (int idx = t; idx < B * D; idx += blockDim.x) {
    const int b = idx >> 7;               // idx / D
    const int d = idx & (D - 1);
    xs[d * XS_STRIDE + b] = x[((size_t)b * N + n) * D + d];
  }
  __syncthreads();

  const int kloc = t >> 6;                // wave-uniform
  const int rem  = t & 63;
  const int o0 = (rem & 15) * 4;
  const int b0 = (rem >> 4) * 4;
  float acc[4][4] = {};

  const float* wp = w + (size_t)(kBase + kloc) * D * O + o0;
#pragma unroll 4
  for (int d = 0; d < D; ++d) {
    const float4 xq = *(const float4*)&xs[d * XS_STRIDE + b0];   // 4 b's at this d
    const float4 wq = *(const float4*)(wp + (size_t)d * O);      // 4 o's at this d
    acc[0][0] += xq.x * wq.x; acc[0][1] += xq.x * wq.y; acc[0][2] += xq.x * wq.z; acc[0][3] += xq.x * wq.w;
    acc[1][0] += xq.y * wq.x; acc[1][1] += xq.y * wq.y; acc[1][2] += xq.y * wq.z; acc[1][3] += xq.y * wq.w;
    acc[2][0] += xq.z * wq.x; acc[2][1] += xq.z * wq.y; acc[2][2] += xq.z * wq.z; acc[2][3] += xq.z * wq.w;
    acc[3][0] += xq.w * wq.x; acc[3][1] += xq.w * wq.y; acc[3][2] += xq.w * wq.z; acc[3][3] += xq.w * wq.w;
  }

  const size_t base = ((size_t)(kloc * N + n)) << 10;   // * BO
#pragma unroll
  for (int bi = 0; bi < 4; ++bi) {
    uint2 pk;
    pk.x = (unsigned)f2bf(acc[bi][0]) | ((unsigned)f2bf(acc[bi][1]) << 16);
    pk.y = (unsigned)f2bf(acc[bi][2]) | ((unsigned)f2bf(acc[bi][3]) << 16);
    *(uint2*)(pre + base + (size_t)(b0 + bi) * O + o0) = pk;   // 8B aligned (o0%4==0)
  }
}

// ---------------------------------------------------------------------------
// Kernel 2: per-row edge histogram (counting-sort pass 1)
// ---------------------------------------------------------------------------
__global__ void hist_kernel(const int* __restrict__ row, int* __restrict__ cnt) {
  const int i = blockIdx.x * 256 + threadIdx.x;
  if (i >= K * E) return;
  const int k = i / E;
  atomicAdd(&cnt[k * N + row[i]], 1);
}

// ---------------------------------------------------------------------------
// Kernel 3: exclusive scan per support -> CSR offsets. One 1024-thread block
// per k. cnt[] is rewritten in place with the exclusive prefix (scatter cursor).
// ---------------------------------------------------------------------------
__global__ __launch_bounds__(1024) void scan_kernel(int* __restrict__ cnt,
                                                    int* __restrict__ offs) {
  const int k = blockIdx.x;
  const int t = threadIdx.x;
  const int lane = t & 63, wid = t >> 6;
  __shared__ int wt[16];
  __shared__ int sbase;
  if (t == 0) { sbase = 0; offs[k * (N + 1)] = 0; }
  __syncthreads();

  for (int c0 = 0; c0 < N; c0 += 1024) {
    const int i = c0 + t;
    const int v = (i < N) ? cnt[k * N + i] : 0;
    int incl = v;
#pragma unroll
    for (int st = 1; st < 64; st <<= 1) {
      const int u = __shfl_up(incl, st, 64);
      if (lane >= st) incl += u;
    }
    if (lane == 63) wt[wid] = incl;
    __syncthreads();
    if (wid == 0) {
      int wv = (lane < 16) ? wt[lane] : 0;
#pragma unroll
      for (int st = 1; st < 16; st <<= 1) {
        const int u = __shfl_up(wv, st, 64);
        if (lane >= st) wv += u;
      }
      if (lane < 16) wt[lane] = wv;
    }
    __syncthreads();
    const int base = sbase + ((wid > 0) ? wt[wid - 1] : 0);
    if (i < N) {
      offs[k * (N + 1) + i + 1] = base + incl;
      cnt[k * N + i] = base + incl - v;     // exclusive prefix -> cursor
    }
    __syncthreads();
    if (t == 0) sbase += wt[15];
    __syncthreads();
  }
}

// ---------------------------------------------------------------------------
// Kernel 4: scatter edges into CSR order (col + fp32 val)
// ---------------------------------------------------------------------------
__global__ void scatter_kernel(const int* __restrict__ row, const int* __restrict__ col,
                               const float* __restrict__ vals,
                               int* __restrict__ cursor, int* __restrict__ scol,
                               float* __restrict__ sval) {
  const int i = blockIdx.x * 256 + threadIdx.x;
  if (i >= K * E) return;
  const int k = i / E;
  const int pos = atomicAdd(&cursor[k * N + row[i]], 1);
  scol[k * E + pos] = col[i];
  sval[k * E + pos] = vals[i];
}

// ---------------------------------------------------------------------------
// Kernel 5: CSR SpMM + fp32 writeout. One block per (kloc, n); thread owns
// bo = 4t..4t+3 (same b, 4 consecutive o). Gathers 8B bf16x4 from pre
// (20.5 MB/support -> L3-resident).
// ---------------------------------------------------------------------------
__global__ __launch_bounds__(256) void spmm_kernel(
    const unsigned short* __restrict__ pre,   // [kCount][N][BO] bf16, local k
    const int* __restrict__ offs, const int* __restrict__ scol,
    const float* __restrict__ sval,
    float* __restrict__ out, int kBase)
{
  const int bid = blockIdx.x;
  const int kloc = bid / N;
  const int n = bid - kloc * N;
  const int k = kBase + kloc;
  const int t = threadIdx.x;
  const int j0 = offs[k * (N + 1) + n];
  const int j1 = offs[k * (N + 1) + n + 1];
  const unsigned short* pk = pre + (((size_t)kloc * N) << 10) + 4 * t;

  float a0 = 0.f, a1 = 0.f, a2 = 0.f, a3 = 0.f;
  for (int j = j0; j < j1; ++j) {
    const int c = scol[k * E + j];        // wave-uniform scalar load
    const float v = sval[k * E + j];
    const ushort4 u = *(const ushort4*)(pk + ((size_t)c << 10));
    a0 += v * bf2f(u.x); a1 += v * bf2f(u.y);
    a2 += v * bf2f(u.z); a3 += v * bf2f(u.w);
  }

  const int b = t >> 4;
  const int o0 = (t & 15) * 4;
  float4 r; r.x = a0; r.y = a1; r.z = a2; r.w = a3;
  *(float4*)(out + ((size_t)b * N + n) * KO + (size_t)k * O + o0) = r;  // 16B aligned
}

// ---------------------------------------------------------------------------
extern "C" void kernel_launch(void* const* d_in, const int* in_sizes, int n_in,
                              void* d_out, int out_size, void* d_ws, size_t ws_size,
                              hipStream_t stream) {
  const float* x    = (const float*)d_in[0];   // fp32 [B,N,D]
  const float* w    = (const float*)d_in[1];   // fp32 [K,D,O]
  const float* vals = (const float*)d_in[2];   // fp32 [K,E]
  const int* row    = (const int*)d_in[3];     // [K,E]
  const int* col    = (const int*)d_in[4];     // [K,E]
  float* out        = (float*)d_out;           // fp32 [B,N,K*O]

  // Workspace carve-up: small arrays first, pre last (size depends on path).
  char* p = (char*)d_ws;
  int* offs = (int*)p;   p += ((size_t)K * (N + 1) * 4 + 15) & ~(size_t)15;  // 120,016
  int* cnt  = (int*)p;   p += ((size_t)K * N * 4 + 15) & ~(size_t)15;        // 120,000
  int* scol = (int*)p;   p += (size_t)K * E * 4;                             // 1,920,000
  float* sval = (float*)p; p += (size_t)K * E * 4;                           // 1,920,000
  unsigned short* pre = (unsigned short*)p;
  const size_t fixed = (size_t)(p - (char*)d_ws);
  const size_t preFull = (size_t)K * N * BO * 2;   // 61,440,000
  const size_t preOne  = (size_t)N * BO * 2;       // 20,480,000
  const bool full = ws_size >= fixed + preFull;    // ws_size constant -> same work every call

  hipMemsetAsync(cnt, 0, (size_t)K * N * 4, stream);

  // CSR build (all supports at once; tiny)
  const int eb = (K * E + 255) / 256;
  hist_kernel<<<eb, 256, 0, stream>>>(row, cnt);
  scan_kernel<<<K, 1024, 0, stream>>>(cnt, offs);
  scatter_kernel<<<eb, 256, 0, stream>>>(row, col, vals, cnt, scol, sval);

  if (full) {
    gemm_pre_kernel<<<N, 64 * K, 0, stream>>>(x, w, pre, 0);
    spmm_kernel<<<K * N, 256, 0, stream>>>(pre, offs, scol, sval, out, 0);
  } else {
    // Reuse one per-support pre buffer; stream order serializes correctly.
    for (int k = 0; k < K; ++k) {
      gemm_pre_kernel<<<N, 64, 0, stream>>>(x, w, pre, k);
      spmm_kernel<<<N, 256, 0, stream>>>(pre, offs, scol, sval, out, k);
    }
  }
  (void)in_sizes; (void)n_in; (void)out_size; (void)preOne;
}

// Round 3
// 423.462 us; speedup vs baseline: 1.1768x; 1.1768x over previous
//
#include <hip/hip_runtime.h>
#include <hip/hip_bf16.h>

// GraphConvolution: x[B,N,D] fp32, W[K,D,O] fp32, COO edges per support (fp32 vals).
// out[b][n][k*O+o] = sum_{edges (r=n,c) in k} val * (x[b][c][:] @ W[k][:,o])
constexpr int B = 16, N = 10000, D = 128, O = 64, K = 3, E = 160000;
constexpr int BO = B * O;   // 1024
constexpr int KO = K * O;   // 192
constexpr int NPB = 8;      // n's per GEMM block

using short8  = __attribute__((ext_vector_type(8))) short;
using floatx4 = __attribute__((ext_vector_type(4))) float;
struct U4 { unsigned a, b, c, d; };

__device__ __forceinline__ float bf2f(unsigned short u) {
  return __uint_as_float(((unsigned int)u) << 16);
}
// fp32 -> bf16, round-half-up (max err 0.5 ulp; cheap: 2 VALU ops)
__device__ __forceinline__ unsigned short f2bf(float f) {
  return (unsigned short)((__float_as_uint(f) + 0x8000u) >> 16);
}
// pack bf16(lo) | bf16(hi)<<16
__device__ __forceinline__ unsigned pkbf(float lo, float hi) {
  return ((__float_as_uint(lo) + 0x8000u) >> 16) |
         ((__float_as_uint(hi) + 0x8000u) & 0xFFFF0000u);
}

// ---------------------------------------------------------------------------
// Kernel 0: repack W[K,D,O] fp32 -> MFMA B-fragment order, bf16.
// wpack[((k*4+t4)*4+dd)*64 + lane][j] = W[k][dd*32+(lane>>4)*8+j][t4*16+(lane&15)]
// 3072 threads total; runs once per launch (~2 us).
// ---------------------------------------------------------------------------
__global__ void wpack_kernel(const float* __restrict__ w, unsigned short* __restrict__ wp) {
  const int i = blockIdx.x * 64 + threadIdx.x;
  if (i >= K * 16 * 64) return;
  const int lane = i & 63;
  const int dd = (i >> 6) & 3;
  const int t4 = (i >> 8) & 3;
  const int k  = i >> 10;
  const int o  = t4 * 16 + (lane & 15);
  const int d0 = dd * 32 + (lane >> 4) * 8;
  unsigned short* dst = wp + (size_t)i * 8;
#pragma unroll
  for (int j = 0; j < 8; ++j)
    dst[j] = f2bf(w[((size_t)k * D + d0 + j) * O + o]);
}

// ---------------------------------------------------------------------------
// Kernel 1: MFMA GEMM. pre[kloc][n][b*64+o] = sum_d x[b][n][d]*W[k][d][o] (bf16)
// blockDim = 64*kCount; wave kloc handles support kBase+kloc. Per n: 4 A-frags
// loaded straight from global x (32B/lane fp32 -> in-reg bf16 pack), 16 MFMA.
// B frags live in registers for all NPB n's. No LDS, no __syncthreads.
// ---------------------------------------------------------------------------
__global__ __launch_bounds__(192) void gemm_mfma_kernel(
    const float* __restrict__ x, const unsigned short* __restrict__ wpk,
    unsigned short* __restrict__ pre, int kBase)
{
  const int t = threadIdx.x;
  const int kloc = t >> 6;
  const int k = kBase + kloc;
  const int lane = t & 63;
  const int col  = lane & 15;   // = A-row b in A-frag, = o-within-tile in B/D
  const int quad = lane >> 4;

  short8 bfr[4][4];             // [t4][dd], 64 VGPRs
#pragma unroll
  for (int t4 = 0; t4 < 4; ++t4)
#pragma unroll
    for (int dd = 0; dd < 4; ++dd)
      bfr[t4][dd] = *(const short8*)(wpk + (size_t)(((k * 4 + t4) * 4 + dd) * 64 + lane) * 8);

  const int n0 = blockIdx.x * NPB;
  const float* xbase = x + (size_t)col * N * D;   // A-row b = col

  for (int nn = 0; nn < NPB; ++nn) {
    const int n = n0 + nn;
    const float* xp = xbase + (size_t)n * D + quad * 8;
    short8 afr[4];
#pragma unroll
    for (int dd = 0; dd < 4; ++dd) {
      const float4 lo = *(const float4*)(xp + dd * 32);
      const float4 hi = *(const float4*)(xp + dd * 32 + 4);
      U4 u;
      u.a = pkbf(lo.x, lo.y); u.b = pkbf(lo.z, lo.w);
      u.c = pkbf(hi.x, hi.y); u.d = pkbf(hi.z, hi.w);
      afr[dd] = __builtin_bit_cast(short8, u);
    }

    floatx4 acc[4] = {};
#pragma unroll
    for (int dd = 0; dd < 4; ++dd)
#pragma unroll
      for (int t4 = 0; t4 < 4; ++t4)
        acc[t4] = __builtin_amdgcn_mfma_f32_16x16x32_bf16(afr[dd], bfr[t4][dd], acc[t4], 0, 0, 0);

    // C/D layout (m89-verified): col = lane&15, row b = quad*4 + reg
    unsigned short* pp = pre + (((size_t)kloc * N + n) << 10) + col;
#pragma unroll
    for (int t4 = 0; t4 < 4; ++t4)
#pragma unroll
      for (int r = 0; r < 4; ++r)
        pp[(quad * 4 + r) * 64 + t4 * 16] = f2bf(acc[t4][r]);
  }
}

// ---------------------------------------------------------------------------
// Kernel 2: per-row edge histogram
// ---------------------------------------------------------------------------
__global__ void hist_kernel(const int* __restrict__ row, int* __restrict__ cnt) {
  const int i = blockIdx.x * 256 + threadIdx.x;
  if (i >= K * E) return;
  const int k = i / E;
  atomicAdd(&cnt[k * N + row[i]], 1);
}

// ---------------------------------------------------------------------------
// Kernel 3: exclusive scan per support -> CSR offsets (cnt becomes cursor)
// ---------------------------------------------------------------------------
__global__ __launch_bounds__(1024) void scan_kernel(int* __restrict__ cnt,
                                                    int* __restrict__ offs) {
  const int k = blockIdx.x;
  const int t = threadIdx.x;
  const int lane = t & 63, wid = t >> 6;
  __shared__ int wt[16];
  __shared__ int sbase;
  if (t == 0) { sbase = 0; offs[k * (N + 1)] = 0; }
  __syncthreads();

  for (int c0 = 0; c0 < N; c0 += 1024) {
    const int i = c0 + t;
    const int v = (i < N) ? cnt[k * N + i] : 0;
    int incl = v;
#pragma unroll
    for (int st = 1; st < 64; st <<= 1) {
      const int u = __shfl_up(incl, st, 64);
      if (lane >= st) incl += u;
    }
    if (lane == 63) wt[wid] = incl;
    __syncthreads();
    if (wid == 0) {
      int wv = (lane < 16) ? wt[lane] : 0;
#pragma unroll
      for (int st = 1; st < 16; st <<= 1) {
        const int u = __shfl_up(wv, st, 64);
        if (lane >= st) wv += u;
      }
      if (lane < 16) wt[lane] = wv;
    }
    __syncthreads();
    const int base = sbase + ((wid > 0) ? wt[wid - 1] : 0);
    if (i < N) {
      offs[k * (N + 1) + i + 1] = base + incl;
      cnt[k * N + i] = base + incl - v;
    }
    __syncthreads();
    if (t == 0) sbase += wt[15];
    __syncthreads();
  }
}

// ---------------------------------------------------------------------------
// Kernel 4: scatter edges into CSR order
// ---------------------------------------------------------------------------
__global__ void scatter_kernel(const int* __restrict__ row, const int* __restrict__ col,
                               const float* __restrict__ vals,
                               int* __restrict__ cursor, int* __restrict__ scol,
                               float* __restrict__ sval) {
  const int i = blockIdx.x * 256 + threadIdx.x;
  if (i >= K * E) return;
  const int k = i / E;
  const int pos = atomicAdd(&cursor[k * N + row[i]], 1);
  scol[k * E + pos] = col[i];
  sval[k * E + pos] = vals[i];
}

// ---------------------------------------------------------------------------
// Kernel 5: CSR SpMM. Block = (kloc,n), 128 threads; thread owns 8 bo
// (one dwordx4 bf16 gather per edge). 2-edge unroll for MLP.
// ---------------------------------------------------------------------------
__global__ __launch_bounds__(128) void spmm_kernel(
    const unsigned short* __restrict__ pre, const int* __restrict__ offs,
    const int* __restrict__ scol, const float* __restrict__ sval,
    float* __restrict__ out, int kBase)
{
  const int bid = blockIdx.x;
  const int kloc = bid / N;
  const int n = bid - kloc * N;
  const int k = kBase + kloc;
  const int t = threadIdx.x;
  const int j0 = offs[k * (N + 1) + n];
  const int j1 = offs[k * (N + 1) + n + 1];
  const unsigned short* pk = pre + (((size_t)kloc * N) << 10) + 8 * t;
  const int* cj = scol + (size_t)k * E;
  const float* vj = sval + (size_t)k * E;

  float a[8] = {};
  int j = j0;
  for (; j + 1 < j1; j += 2) {
    const int c0 = cj[j], c1 = cj[j + 1];
    const float v0 = vj[j], v1 = vj[j + 1];
    const short8 u0 = *(const short8*)(pk + ((size_t)c0 << 10));
    const short8 u1 = *(const short8*)(pk + ((size_t)c1 << 10));
#pragma unroll
    for (int q = 0; q < 8; ++q)
      a[q] += v0 * bf2f((unsigned short)u0[q]) + v1 * bf2f((unsigned short)u1[q]);
  }
  if (j < j1) {
    const int c0 = cj[j];
    const float v0 = vj[j];
    const short8 u0 = *(const short8*)(pk + ((size_t)c0 << 10));
#pragma unroll
    for (int q = 0; q < 8; ++q)
      a[q] += v0 * bf2f((unsigned short)u0[q]);
  }

  const int b = t >> 3;
  const int o0 = (t & 7) * 8;
  float* op = out + ((size_t)b * N + n) * KO + (size_t)k * O + o0;
  *(float4*)op = *(const float4*)&a[0];
  *(float4*)(op + 4) = *(const float4*)&a[4];
}

// ---------------------------------------------------------------------------
extern "C" void kernel_launch(void* const* d_in, const int* in_sizes, int n_in,
                              void* d_out, int out_size, void* d_ws, size_t ws_size,
                              hipStream_t stream) {
  const float* x    = (const float*)d_in[0];
  const float* w    = (const float*)d_in[1];
  const float* vals = (const float*)d_in[2];
  const int* row    = (const int*)d_in[3];
  const int* col    = (const int*)d_in[4];
  float* out        = (float*)d_out;

  char* p = (char*)d_ws;
  int* offs = (int*)p;            p += ((size_t)K * (N + 1) * 4 + 15) & ~(size_t)15;
  int* cnt  = (int*)p;            p += (size_t)K * N * 4;        // 120000, 16B-mult
  int* scol = (int*)p;            p += (size_t)K * E * 4;
  float* sval = (float*)p;        p += (size_t)K * E * 4;
  unsigned short* wpk = (unsigned short*)p; p += (size_t)K * 16 * 64 * 8 * 2;  // 49152
  unsigned short* pre = (unsigned short*)p;
  const size_t fixed = (size_t)(p - (char*)d_ws);
  const size_t preFull = (size_t)K * N * BO * 2;
  const bool full = ws_size >= fixed + preFull;  // ws_size constant across calls

  hipMemsetAsync(cnt, 0, (size_t)K * N * 4, stream);

  wpack_kernel<<<48, 64, 0, stream>>>(w, wpk);
  const int eb = (K * E + 255) / 256;
  hist_kernel<<<eb, 256, 0, stream>>>(row, cnt);
  scan_kernel<<<K, 1024, 0, stream>>>(cnt, offs);
  scatter_kernel<<<eb, 256, 0, stream>>>(row, col, vals, cnt, scol, sval);

  if (full) {
    gemm_mfma_kernel<<<N / NPB, 64 * K, 0, stream>>>(x, wpk, pre, 0);
    spmm_kernel<<<K * N, 128, 0, stream>>>(pre, offs, scol, sval, out, 0);
  } else {
    for (int k = 0; k < K; ++k) {
      gemm_mfma_kernel<<<N / NPB, 64, 0, stream>>>(x, wpk, pre, k);
      spmm_kernel<<<N, 128, 0, stream>>>(pre, offs, scol, sval, out, k);
    }
  }
  (void)in_sizes; (void)n_in; (void)out_size;
}

// Round 4
// 419.922 us; speedup vs baseline: 1.1867x; 1.0084x over previous
//
#include <hip/hip_runtime.h>
#include <hip/hip_bf16.h>

// GraphConvolution: x[B,N,D] fp32, W[K,D,O] fp32, COO edges per support (fp32 vals).
// out[b][n][k*O+o] = sum_{edges (r=n,c) in k} val * (x[b][c][:] @ W[k][:,o])
constexpr int B = 16, N = 10000, D = 128, O = 64, K = 3, E = 160000;
constexpr int BO = B * O;   // 1024
constexpr int KO = K * O;   // 192
constexpr int NPB = 8;      // n's per GEMM block

using short8  = __attribute__((ext_vector_type(8))) short;
using floatx4 = __attribute__((ext_vector_type(4))) float;
struct U4 { unsigned a, b, c, d; };

__device__ __forceinline__ float bf2f(unsigned short u) {
  return __uint_as_float(((unsigned int)u) << 16);
}
// fp32 -> bf16, round-half-up (max err 0.5 ulp)
__device__ __forceinline__ unsigned short f2bf(float f) {
  return (unsigned short)((__float_as_uint(f) + 0x8000u) >> 16);
}
__device__ __forceinline__ unsigned pkbf(float lo, float hi) {
  return ((__float_as_uint(lo) + 0x8000u) >> 16) |
         ((__float_as_uint(hi) + 0x8000u) & 0xFFFF0000u);
}

// ---------------------------------------------------------------------------
// Kernel 0: repack W[K,D,O] fp32 -> MFMA fragment order, bf16.
// wpack[((k*4+t4)*4+dd)*64 + lane][j] = W[k][dd*32+(lane>>4)*8+j][t4*16+(lane&15)]
// Same mapping serves as A-frag (m=o, k=d) after the operand swap.
// ---------------------------------------------------------------------------
__global__ void wpack_kernel(const float* __restrict__ w, unsigned short* __restrict__ wp) {
  const int i = blockIdx.x * 64 + threadIdx.x;
  if (i >= K * 16 * 64) return;
  const int lane = i & 63;
  const int dd = (i >> 6) & 3;
  const int t4 = (i >> 8) & 3;
  const int k  = i >> 10;
  const int o  = t4 * 16 + (lane & 15);
  const int d0 = dd * 32 + (lane >> 4) * 8;
  unsigned short* dst = wp + (size_t)i * 8;
#pragma unroll
  for (int j = 0; j < 8; ++j)
    dst[j] = f2bf(w[((size_t)k * D + d0 + j) * O + o]);
}

// ---------------------------------------------------------------------------
// Kernel 1: MFMA GEMM. pre[kloc][n][b*64+o] = sum_d x[b][n][d]*W[k][d][o] (bf16)
// A = W-frag (m=o_loc, k=d), B = x-frag (k=d, n=b)  [operand-swapped so D's
// row axis = o]. D layout: col(lane&15)=b, row(quad*4+r)=o_loc -> lane owns 4
// consecutive o at fixed b => one 8B store per t4 (was 16x 2B scalar stores).
// ---------------------------------------------------------------------------
__global__ __launch_bounds__(192) void gemm_mfma_kernel(
    const float* __restrict__ x, const unsigned short* __restrict__ wpk,
    unsigned short* __restrict__ pre, int kBase)
{
  const int t = threadIdx.x;
  const int kloc = t >> 6;
  const int k = kBase + kloc;
  const int lane = t & 63;
  const int col  = lane & 15;
  const int quad = lane >> 4;

  short8 wfr[4][4];             // [t4][dd]: A-frag, lane holds W[d=quad*8+j][o=t4*16+col]
#pragma unroll
  for (int t4 = 0; t4 < 4; ++t4)
#pragma unroll
    for (int dd = 0; dd < 4; ++dd)
      wfr[t4][dd] = *(const short8*)(wpk + (size_t)(((k * 4 + t4) * 4 + dd) * 64 + lane) * 8);

  const int n0 = blockIdx.x * NPB;
  const float* xbase = x + (size_t)col * N * D;   // B-frag n-axis = b = col

  for (int nn = 0; nn < NPB; ++nn) {
    const int n = n0 + nn;
    const float* xp = xbase + (size_t)n * D + quad * 8;
    short8 xfr[4];
#pragma unroll
    for (int dd = 0; dd < 4; ++dd) {
      const float4 lo = *(const float4*)(xp + dd * 32);
      const float4 hi = *(const float4*)(xp + dd * 32 + 4);
      U4 u;
      u.a = pkbf(lo.x, lo.y); u.b = pkbf(lo.z, lo.w);
      u.c = pkbf(hi.x, hi.y); u.d = pkbf(hi.z, hi.w);
      xfr[dd] = __builtin_bit_cast(short8, u);
    }

    floatx4 acc[4] = {};
#pragma unroll
    for (int dd = 0; dd < 4; ++dd)
#pragma unroll
      for (int t4 = 0; t4 < 4; ++t4)
        acc[t4] = __builtin_amdgcn_mfma_f32_16x16x32_bf16(wfr[t4][dd], xfr[dd], acc[t4], 0, 0, 0);

    // D: col=b, row=o_loc=quad*4+r; o = t4*16 + o_loc. 4 consecutive o -> 8B.
    unsigned short* pp = pre + (((size_t)kloc * N + n) << 10) + col * 64 + quad * 4;
#pragma unroll
    for (int t4 = 0; t4 < 4; ++t4) {
      uint2 pk2;
      pk2.x = pkbf(acc[t4][0], acc[t4][1]);
      pk2.y = pkbf(acc[t4][2], acc[t4][3]);
      *(uint2*)(pp + t4 * 16) = pk2;
    }
  }
}

// ---------------------------------------------------------------------------
// Kernel 2: per-row edge histogram
// ---------------------------------------------------------------------------
__global__ void hist_kernel(const int* __restrict__ row, int* __restrict__ cnt) {
  const int i = blockIdx.x * 256 + threadIdx.x;
  if (i >= K * E) return;
  const int k = i / E;
  atomicAdd(&cnt[k * N + row[i]], 1);
}

// ---------------------------------------------------------------------------
// Kernel 3: exclusive scan per support -> CSR offsets (cnt becomes cursor)
// ---------------------------------------------------------------------------
__global__ __launch_bounds__(1024) void scan_kernel(int* __restrict__ cnt,
                                                    int* __restrict__ offs) {
  const int k = blockIdx.x;
  const int t = threadIdx.x;
  const int lane = t & 63, wid = t >> 6;
  __shared__ int wt[16];
  __shared__ int sbase;
  if (t == 0) { sbase = 0; offs[k * (N + 1)] = 0; }
  __syncthreads();

  for (int c0 = 0; c0 < N; c0 += 1024) {
    const int i = c0 + t;
    const int v = (i < N) ? cnt[k * N + i] : 0;
    int incl = v;
#pragma unroll
    for (int st = 1; st < 64; st <<= 1) {
      const int u = __shfl_up(incl, st, 64);
      if (lane >= st) incl += u;
    }
    if (lane == 63) wt[wid] = incl;
    __syncthreads();
    if (wid == 0) {
      int wv = (lane < 16) ? wt[lane] : 0;
#pragma unroll
      for (int st = 1; st < 16; st <<= 1) {
        const int u = __shfl_up(wv, st, 64);
        if (lane >= st) wv += u;
      }
      if (lane < 16) wt[lane] = wv;
    }
    __syncthreads();
    const int base = sbase + ((wid > 0) ? wt[wid - 1] : 0);
    if (i < N) {
      offs[k * (N + 1) + i + 1] = base + incl;
      cnt[k * N + i] = base + incl - v;
    }
    __syncthreads();
    if (t == 0) sbase += wt[15];
    __syncthreads();
  }
}

// ---------------------------------------------------------------------------
// Kernel 4: scatter edges into CSR order
// ---------------------------------------------------------------------------
__global__ void scatter_kernel(const int* __restrict__ row, const int* __restrict__ col,
                               const float* __restrict__ vals,
                               int* __restrict__ cursor, int* __restrict__ scol,
                               float* __restrict__ sval) {
  const int i = blockIdx.x * 256 + threadIdx.x;
  if (i >= K * E) return;
  const int k = i / E;
  const int pos = atomicAdd(&cursor[k * N + row[i]], 1);
  scol[k * E + pos] = col[i];
  sval[k * E + pos] = vals[i];
}

// ---------------------------------------------------------------------------
// Kernel 5: CSR SpMM. Block = (kloc,n), 128 threads; thread owns 8 bo.
// 4-edge unroll -> 4 dwordx4 gathers in flight per thread.
// ---------------------------------------------------------------------------
__global__ __launch_bounds__(128) void spmm_kernel(
    const unsigned short* __restrict__ pre, const int* __restrict__ offs,
    const int* __restrict__ scol, const float* __restrict__ sval,
    float* __restrict__ out, int kBase)
{
  const int bid = blockIdx.x;
  const int kloc = bid / N;
  const int n = bid - kloc * N;
  const int k = kBase + kloc;
  const int t = threadIdx.x;
  const int j0 = __builtin_amdgcn_readfirstlane(offs[k * (N + 1) + n]);
  const int j1 = __builtin_amdgcn_readfirstlane(offs[k * (N + 1) + n + 1]);
  const unsigned short* pk = pre + (((size_t)kloc * N) << 10) + 8 * t;
  const int* cj = scol + (size_t)k * E;
  const float* vj = sval + (size_t)k * E;

  float a[8] = {};
  int j = j0;
  for (; j + 3 < j1; j += 4) {
    const int c0 = __builtin_amdgcn_readfirstlane(cj[j]);
    const int c1 = __builtin_amdgcn_readfirstlane(cj[j + 1]);
    const int c2 = __builtin_amdgcn_readfirstlane(cj[j + 2]);
    const int c3 = __builtin_amdgcn_readfirstlane(cj[j + 3]);
    const float v0 = vj[j], v1 = vj[j + 1], v2 = vj[j + 2], v3 = vj[j + 3];
    const short8 u0 = *(const short8*)(pk + ((size_t)c0 << 10));
    const short8 u1 = *(const short8*)(pk + ((size_t)c1 << 10));
    const short8 u2 = *(const short8*)(pk + ((size_t)c2 << 10));
    const short8 u3 = *(const short8*)(pk + ((size_t)c3 << 10));
#pragma unroll
    for (int q = 0; q < 8; ++q)
      a[q] += v0 * bf2f((unsigned short)u0[q]) + v1 * bf2f((unsigned short)u1[q]) +
              v2 * bf2f((unsigned short)u2[q]) + v3 * bf2f((unsigned short)u3[q]);
  }
  for (; j < j1; ++j) {
    const int c0 = __builtin_amdgcn_readfirstlane(cj[j]);
    const float v0 = vj[j];
    const short8 u0 = *(const short8*)(pk + ((size_t)c0 << 10));
#pragma unroll
    for (int q = 0; q < 8; ++q)
      a[q] += v0 * bf2f((unsigned short)u0[q]);
  }

  const int b = t >> 3;
  const int o0 = (t & 7) * 8;
  float* op = out + ((size_t)b * N + n) * KO + (size_t)k * O + o0;
  *(float4*)op = *(const float4*)&a[0];
  *(float4*)(op + 4) = *(const float4*)&a[4];
}

// ---------------------------------------------------------------------------
extern "C" void kernel_launch(void* const* d_in, const int* in_sizes, int n_in,
                              void* d_out, int out_size, void* d_ws, size_t ws_size,
                              hipStream_t stream) {
  const float* x    = (const float*)d_in[0];
  const float* w    = (const float*)d_in[1];
  const float* vals = (const float*)d_in[2];
  const int* row    = (const int*)d_in[3];
  const int* col    = (const int*)d_in[4];
  float* out        = (float*)d_out;

  char* p = (char*)d_ws;
  int* offs = (int*)p;            p += ((size_t)K * (N + 1) * 4 + 15) & ~(size_t)15;
  int* cnt  = (int*)p;            p += (size_t)K * N * 4;
  int* scol = (int*)p;            p += (size_t)K * E * 4;
  float* sval = (float*)p;        p += (size_t)K * E * 4;
  unsigned short* wpk = (unsigned short*)p; p += (size_t)K * 16 * 64 * 8 * 2;
  unsigned short* pre = (unsigned short*)p;
  const size_t fixed = (size_t)(p - (char*)d_ws);
  const size_t preFull = (size_t)K * N * BO * 2;
  const bool full = ws_size >= fixed + preFull;  // ws_size constant across calls

  hipMemsetAsync(cnt, 0, (size_t)K * N * 4, stream);

  wpack_kernel<<<48, 64, 0, stream>>>(w, wpk);
  const int eb = (K * E + 255) / 256;
  hist_kernel<<<eb, 256, 0, stream>>>(row, cnt);
  scan_kernel<<<K, 1024, 0, stream>>>(cnt, offs);
  scatter_kernel<<<eb, 256, 0, stream>>>(row, col, vals, cnt, scol, sval);

  if (full) {
    gemm_mfma_kernel<<<N / NPB, 64 * K, 0, stream>>>(x, wpk, pre, 0);
    spmm_kernel<<<K * N, 128, 0, stream>>>(pre, offs, scol, sval, out, 0);
  } else {
    for (int k = 0; k < K; ++k) {
      gemm_mfma_kernel<<<N / NPB, 64, 0, stream>>>(x, wpk, pre, k);
      spmm_kernel<<<N, 128, 0, stream>>>(pre, offs, scol, sval, out, k);
    }
  }
  (void)in_sizes; (void)n_in; (void)out_size;
}

// Round 5
// 397.338 us; speedup vs baseline: 1.2542x; 1.0568x over previous
//
#include <hip/hip_runtime.h>
#include <hip/hip_bf16.h>

// GraphConvolution: x[B,N,D] fp32, W[K,D,O] fp32, COO edges per support (fp32 vals).
// out[b][n][k*O+o] = sum_{edges (r=n,c) in k} val * (x[b][c][:] @ W[k][:,o])
constexpr int B = 16, N = 10000, D = 128, O = 64, K = 3, E = 160000;
constexpr int BO = B * O;   // 1024
constexpr int KO = K * O;   // 192
constexpr int NPB = 8;      // n's per GEMM block
constexpr int G = 8;        // spmm bo-groups, pinned to XCDs via blockIdx%8
constexpr int ROWS = 8;     // rows per spmm block
constexpr int NCH = N / ROWS;  // 1250

using short8  = __attribute__((ext_vector_type(8))) short;
using floatx4 = __attribute__((ext_vector_type(4))) float;
struct U4 { unsigned a, b, c, d; };

__device__ __forceinline__ float bf2f(unsigned short u) {
  return __uint_as_float(((unsigned int)u) << 16);
}
// fp32 -> bf16, round-half-up (max err 0.5 ulp)
__device__ __forceinline__ unsigned short f2bf(float f) {
  return (unsigned short)((__float_as_uint(f) + 0x8000u) >> 16);
}
__device__ __forceinline__ unsigned pkbf(float lo, float hi) {
  return ((__float_as_uint(lo) + 0x8000u) >> 16) |
         ((__float_as_uint(hi) + 0x8000u) & 0xFFFF0000u);
}

// ---------------------------------------------------------------------------
// Kernel 0: repack W[K,D,O] fp32 -> MFMA A-fragment order (m=o, k=d), bf16.
// wpack[((k*4+t4)*4+dd)*64 + lane][j] = W[k][dd*32+(lane>>4)*8+j][t4*16+(lane&15)]
// ---------------------------------------------------------------------------
__global__ void wpack_kernel(const float* __restrict__ w, unsigned short* __restrict__ wp) {
  const int i = blockIdx.x * 64 + threadIdx.x;
  if (i >= K * 16 * 64) return;
  const int lane = i & 63;
  const int dd = (i >> 6) & 3;
  const int t4 = (i >> 8) & 3;
  const int k  = i >> 10;
  const int o  = t4 * 16 + (lane & 15);
  const int d0 = dd * 32 + (lane >> 4) * 8;
  unsigned short* dst = wp + (size_t)i * 8;
#pragma unroll
  for (int j = 0; j < 8; ++j)
    dst[j] = f2bf(w[((size_t)k * D + d0 + j) * O + o]);
}

// ---------------------------------------------------------------------------
// Kernel 1: MFMA GEMM. pre[kloc][n][b*64+o] = sum_d x[b][n][d]*W[k][d][o] (bf16)
// A = W-frag (m=o), B = x-frag (n=b); D: col=b, row=o_loc -> 8B stores.
// ---------------------------------------------------------------------------
__global__ __launch_bounds__(192) void gemm_mfma_kernel(
    const float* __restrict__ x, const unsigned short* __restrict__ wpk,
    unsigned short* __restrict__ pre, int kBase)
{
  const int t = threadIdx.x;
  const int kloc = t >> 6;
  const int k = kBase + kloc;
  const int lane = t & 63;
  const int col  = lane & 15;
  const int quad = lane >> 4;

  short8 wfr[4][4];             // [t4][dd]
#pragma unroll
  for (int t4 = 0; t4 < 4; ++t4)
#pragma unroll
    for (int dd = 0; dd < 4; ++dd)
      wfr[t4][dd] = *(const short8*)(wpk + (size_t)(((k * 4 + t4) * 4 + dd) * 64 + lane) * 8);

  const int n0 = blockIdx.x * NPB;
  const float* xbase = x + (size_t)col * N * D;   // B-frag n-axis = b = col

  for (int nn = 0; nn < NPB; ++nn) {
    const int n = n0 + nn;
    const float* xp = xbase + (size_t)n * D + quad * 8;
    short8 xfr[4];
#pragma unroll
    for (int dd = 0; dd < 4; ++dd) {
      const float4 lo = *(const float4*)(xp + dd * 32);
      const float4 hi = *(const float4*)(xp + dd * 32 + 4);
      U4 u;
      u.a = pkbf(lo.x, lo.y); u.b = pkbf(lo.z, lo.w);
      u.c = pkbf(hi.x, hi.y); u.d = pkbf(hi.z, hi.w);
      xfr[dd] = __builtin_bit_cast(short8, u);
    }

    floatx4 acc[4] = {};
#pragma unroll
    for (int dd = 0; dd < 4; ++dd)
#pragma unroll
      for (int t4 = 0; t4 < 4; ++t4)
        acc[t4] = __builtin_amdgcn_mfma_f32_16x16x32_bf16(wfr[t4][dd], xfr[dd], acc[t4], 0, 0, 0);

    unsigned short* pp = pre + (((size_t)kloc * N + n) << 10) + col * 64 + quad * 4;
#pragma unroll
    for (int t4 = 0; t4 < 4; ++t4) {
      uint2 pk2;
      pk2.x = pkbf(acc[t4][0], acc[t4][1]);
      pk2.y = pkbf(acc[t4][2], acc[t4][3]);
      *(uint2*)(pp + t4 * 16) = pk2;
    }
  }
}

// ---------------------------------------------------------------------------
// Kernel 2: per-row edge histogram
// ---------------------------------------------------------------------------
__global__ void hist_kernel(const int* __restrict__ row, int* __restrict__ cnt) {
  const int i = blockIdx.x * 256 + threadIdx.x;
  if (i >= K * E) return;
  const int k = i / E;
  atomicAdd(&cnt[k * N + row[i]], 1);
}

// ---------------------------------------------------------------------------
// Kernel 3: exclusive scan per support -> CSR offsets (cnt becomes cursor)
// ---------------------------------------------------------------------------
__global__ __launch_bounds__(1024) void scan_kernel(int* __restrict__ cnt,
                                                    int* __restrict__ offs) {
  const int k = blockIdx.x;
  const int t = threadIdx.x;
  const int lane = t & 63, wid = t >> 6;
  __shared__ int wt[16];
  __shared__ int sbase;
  if (t == 0) { sbase = 0; offs[k * (N + 1)] = 0; }
  __syncthreads();

  for (int c0 = 0; c0 < N; c0 += 1024) {
    const int i = c0 + t;
    const int v = (i < N) ? cnt[k * N + i] : 0;
    int incl = v;
#pragma unroll
    for (int st = 1; st < 64; st <<= 1) {
      const int u = __shfl_up(incl, st, 64);
      if (lane >= st) incl += u;
    }
    if (lane == 63) wt[wid] = incl;
    __syncthreads();
    if (wid == 0) {
      int wv = (lane < 16) ? wt[lane] : 0;
#pragma unroll
      for (int st = 1; st < 16; st <<= 1) {
        const int u = __shfl_up(wv, st, 64);
        if (lane >= st) wv += u;
      }
      if (lane < 16) wt[lane] = wv;
    }
    __syncthreads();
    const int base = sbase + ((wid > 0) ? wt[wid - 1] : 0);
    if (i < N) {
      offs[k * (N + 1) + i + 1] = base + incl;
      cnt[k * N + i] = base + incl - v;
    }
    __syncthreads();
    if (t == 0) sbase += wt[15];
    __syncthreads();
  }
}

// ---------------------------------------------------------------------------
// Kernel 4: scatter edges into CSR order
// ---------------------------------------------------------------------------
__global__ void scatter_kernel(const int* __restrict__ row, const int* __restrict__ col,
                               const float* __restrict__ vals,
                               int* __restrict__ cursor, int* __restrict__ scol,
                               float* __restrict__ sval) {
  const int i = blockIdx.x * 256 + threadIdx.x;
  if (i >= K * E) return;
  const int k = i / E;
  const int pos = atomicAdd(&cursor[k * N + row[i]], 1);
  scol[k * E + pos] = col[i];
  sval[k * E + pos] = vals[i];
}

// ---------------------------------------------------------------------------
// Kernel 5: CSR SpMM, XCD-partitioned by bo-slice. Block = 1 wave, handles
// (g = blockIdx%8, k, 8 rows); owns bo [g*128, g*128+128) -> per-XCD active
// footprint = 20.5/8 = 2.56 MB < 4 MB L2, each pre line reused ~16x from L2.
// k-major block order keeps one support active at a time.
// ---------------------------------------------------------------------------
__global__ __launch_bounds__(64) void spmm_kernel(
    const unsigned short* __restrict__ pre, const int* __restrict__ offs,
    const int* __restrict__ scol, const float* __restrict__ sval,
    float* __restrict__ out, int kBase)
{
  const int bid = blockIdx.x;
  const int g   = bid & 7;
  const int t2  = bid >> 3;
  const int nc  = t2 % NCH;
  const int kloc = t2 / NCH;            // k-major: all nc for k before k+1
  const int k = kBase + kloc;
  const int lane = threadIdx.x;

  const int bo = g * 128 + 2 * lane;    // 2 consecutive bo per lane
  const int b = bo >> 6;
  const int o = bo & 63;
  const unsigned short* pk = pre + (((size_t)kloc * N) << 10) + bo;
  const int* cj = scol + (size_t)k * E;
  const float* vj = sval + (size_t)k * E;
  const int* op = offs + k * (N + 1) + nc * ROWS;

  for (int r = 0; r < ROWS; ++r) {
    const int j0 = __builtin_amdgcn_readfirstlane(op[r]);
    const int j1 = __builtin_amdgcn_readfirstlane(op[r + 1]);
    float a0 = 0.f, a1 = 0.f;
    int j = j0;
    for (; j + 7 < j1; j += 8) {
      unsigned u[8]; float v[8];
#pragma unroll
      for (int i = 0; i < 8; ++i) {
        const int c = __builtin_amdgcn_readfirstlane(cj[j + i]);  // SGPR base
        u[i] = *(const unsigned*)(pk + ((size_t)c << 10));
        v[i] = vj[j + i];
      }
#pragma unroll
      for (int i = 0; i < 8; ++i) {
        a0 += v[i] * bf2f((unsigned short)(u[i] & 0xFFFFu));
        a1 += v[i] * bf2f((unsigned short)(u[i] >> 16));
      }
    }
    for (; j < j1; ++j) {
      const int c = __builtin_amdgcn_readfirstlane(cj[j]);
      const float v = vj[j];
      const unsigned u = *(const unsigned*)(pk + ((size_t)c << 10));
      a0 += v * bf2f((unsigned short)(u & 0xFFFFu));
      a1 += v * bf2f((unsigned short)(u >> 16));
    }
    const int n = nc * ROWS + r;
    float2 st; st.x = a0; st.y = a1;
    *(float2*)(out + ((size_t)b * N + n) * KO + (size_t)k * O + o) = st;  // 8B aligned
  }
}

// ---------------------------------------------------------------------------
extern "C" void kernel_launch(void* const* d_in, const int* in_sizes, int n_in,
                              void* d_out, int out_size, void* d_ws, size_t ws_size,
                              hipStream_t stream) {
  const float* x    = (const float*)d_in[0];
  const float* w    = (const float*)d_in[1];
  const float* vals = (const float*)d_in[2];
  const int* row    = (const int*)d_in[3];
  const int* col    = (const int*)d_in[4];
  float* out        = (float*)d_out;

  char* p = (char*)d_ws;
  int* offs = (int*)p;            p += ((size_t)K * (N + 1) * 4 + 15) & ~(size_t)15;
  int* cnt  = (int*)p;            p += (size_t)K * N * 4;
  int* scol = (int*)p;            p += (size_t)K * E * 4;
  float* sval = (float*)p;        p += (size_t)K * E * 4;
  unsigned short* wpk = (unsigned short*)p; p += (size_t)K * 16 * 64 * 8 * 2;
  unsigned short* pre = (unsigned short*)p;
  const size_t fixed = (size_t)(p - (char*)d_ws);
  const size_t preFull = (size_t)K * N * BO * 2;
  const bool full = ws_size >= fixed + preFull;  // ws_size constant across calls

  hipMemsetAsync(cnt, 0, (size_t)K * N * 4, stream);

  wpack_kernel<<<48, 64, 0, stream>>>(w, wpk);
  const int eb = (K * E + 255) / 256;
  hist_kernel<<<eb, 256, 0, stream>>>(row, cnt);
  scan_kernel<<<K, 1024, 0, stream>>>(cnt, offs);
  scatter_kernel<<<eb, 256, 0, stream>>>(row, col, vals, cnt, scol, sval);

  if (full) {
    gemm_mfma_kernel<<<N / NPB, 64 * K, 0, stream>>>(x, wpk, pre, 0);
    spmm_kernel<<<K * NCH * G, 64, 0, stream>>>(pre, offs, scol, sval, out, 0);
  } else {
    for (int k = 0; k < K; ++k) {
      gemm_mfma_kernel<<<N / NPB, 64, 0, stream>>>(x, wpk, pre, k);
      spmm_kernel<<<NCH * G, 64, 0, stream>>>(pre, offs, scol, sval, out, k);
    }
  }
  (void)in_sizes; (void)n_in; (void)out_size;
}